// Round 14
// baseline (456.123 us; speedup 1.0000x reference)
//
#include <hip/hip_runtime.h>
#include <math.h>

#define NPOINTS (1 << 21)
#define LVL 16
#define TSIZE (1 << 19)
#define TMASK (TSIZE - 1)
#define PRIME2 2654435761u

// Morton bucket grid: 512 x 512 bins (~8 pts/bin) -- R11's proven config.
#define GBITS 9
#define GRES (1 << GBITS)
#define NBINS (1 << (2 * GBITS))
#define SCAN_CHUNK 1024
#define NCHUNKS (NBINS / SCAN_CHUNK)   // 256

// LDS dense grids for levels 0..3 (N = 16,22,31,42; odd strides for banks)
#define NLDS 4
#define GPAD16 1792                    // f32x4 slots = 28,672 B LDS

typedef float f32x2 __attribute__((ext_vector_type(2)));
typedef float f32x4 __attribute__((ext_vector_type(4)));

struct Params {
    int   n[LVL];
    float fn[LVL];
    int   goff[NLDS];    // entry offset of each LDS level grid
    int   gstr[NLDS];    // row stride (N|1)
};

__device__ __forceinline__ unsigned part1by1(unsigned v) {
    v &= 0xFFFFu;
    v = (v | (v << 8)) & 0x00FF00FFu;
    v = (v | (v << 4)) & 0x0F0F0F0Fu;
    v = (v | (v << 2)) & 0x33333333u;
    v = (v | (v << 1)) & 0x55555555u;
    return v;
}

__device__ __forceinline__ unsigned morton_key(f32x2 pt) {
    int kx = (int)(pt.x * (float)GRES);
    int ky = (int)(pt.y * (float)GRES);
    kx = min(max(kx, 0), GRES - 1);
    ky = min(max(ky, 0), GRES - 1);
    return (part1by1((unsigned)ky) << 1) | part1by1((unsigned)kx);
}

// Plain 4-gather bilinear lookup (bit-identical to reference math).
__device__ __forceinline__ f32x2 level_feat(const f32x2* __restrict__ tables,
                                            int l, int N, float fN, f32x2 pt)
{
    float sx = pt.x * fN;
    float sy = pt.y * fN;
    float fx = floorf(sx);
    float fy = floorf(sy);
    float wx = sx - fx;
    float wy = sy - fy;
    int ix = (int)fx;
    int iy = (int)fy;

    int cx0 = (ix     >= N) ? ix - N     : ix;
    int cx1 = (ix + 1 >= N) ? ix + 1 - N : ix + 1;
    int cy0 = (iy     >= N) ? iy - N     : iy;
    int cy1 = (iy + 1 >= N) ? iy + 1 - N : iy + 1;

    unsigned hy0 = (unsigned)cy0 * PRIME2;
    unsigned hy1 = (unsigned)cy1 * PRIME2;

    const f32x2* tbl = tables + (size_t)l * TSIZE;
    f32x2 c00 = tbl[(int)(((unsigned)cx0 ^ hy0) & TMASK)];
    f32x2 c10 = tbl[(int)(((unsigned)cx1 ^ hy0) & TMASK)];
    f32x2 c01 = tbl[(int)(((unsigned)cx0 ^ hy1) & TMASK)];
    f32x2 c11 = tbl[(int)(((unsigned)cx1 ^ hy1) & TMASK)];

    float omx = 1.0f - wx, omy = 1.0f - wy;
    float f0x = c00.x * omx + c10.x * wx;
    float f0y = c00.y * omx + c10.y * wx;
    float f1x = c01.x * omx + c11.x * wx;
    float f1y = c01.y * omx + c11.y * wx;

    f32x2 r;
    r.x = f0x * omy + f1x * wy;
    r.y = f0y * omy + f1y * wy;
    return r;
}

// Same math, corners served from the LDS dense grid (no TA/TCP traffic).
__device__ __forceinline__ f32x2 level_feat_lds(const f32x2* __restrict__ gl,
                                                int base, int st,
                                                int N, float fN, f32x2 pt)
{
    float sx = pt.x * fN;
    float sy = pt.y * fN;
    float fx = floorf(sx);
    float fy = floorf(sy);
    float wx = sx - fx;
    float wy = sy - fy;
    int ix = (int)fx;
    int iy = (int)fy;

    int cx0 = (ix     >= N) ? ix - N     : ix;
    int cx1 = (ix + 1 >= N) ? ix + 1 - N : ix + 1;
    int cy0 = (iy     >= N) ? iy - N     : iy;
    int cy1 = (iy + 1 >= N) ? iy + 1 - N : iy + 1;

    int r0 = base + cy0 * st;
    int r1 = base + cy1 * st;
    f32x2 c00 = gl[r0 + cx0];
    f32x2 c10 = gl[r0 + cx1];
    f32x2 c01 = gl[r1 + cx0];
    f32x2 c11 = gl[r1 + cx1];

    float omx = 1.0f - wx, omy = 1.0f - wy;
    float f0x = c00.x * omx + c10.x * wx;
    float f0y = c00.y * omx + c10.y * wx;
    float f1x = c01.x * omx + c11.x * wx;
    float f1y = c01.y * omx + c11.y * wx;

    f32x2 r;
    r.x = f0x * omy + f1x * wy;
    r.y = f0y * omy + f1y * wy;
    return r;
}

// ---- Grid builder: de-hash levels 0..3 into dense [cy][cx] grids in ws.
__global__ __launch_bounds__(256) void build_grids_kernel(
    const f32x2* __restrict__ tables, f32x2* __restrict__ grids, Params P)
{
    int t = blockIdx.x * 256 + threadIdx.x;
    if (t >= GPAD16 * 2) return;
    f32x2 v = { 0.0f, 0.0f };
    #pragma unroll
    for (int li = 0; li < NLDS; ++li) {
        int base = P.goff[li], st = P.gstr[li], N = P.n[li];
        int local = t - base;
        if (local >= 0 && local < st * N) {
            int cy = local / st;
            int cx = local - cy * st;
            if (cx < N) {
                unsigned h = ((unsigned)cx ^ ((unsigned)cy * PRIME2)) & TMASK;
                v = tables[(size_t)li * TSIZE + h];
            }
        }
    }
    grids[t] = v;
}

// ---- Sort step 1: histogram of Morton keys.
__global__ __launch_bounds__(256) void hist_kernel(
    const f32x2* __restrict__ xy, unsigned* __restrict__ hist)
{
    int p = blockIdx.x * 256 + threadIdx.x;
    f32x2 pt = __builtin_nontemporal_load(&xy[p]);
    atomicAdd(&hist[morton_key(pt)], 1u);
}

// ---- Sort step 2a: per-chunk exclusive scan, chunk totals.
__global__ __launch_bounds__(SCAN_CHUNK) void scan_local_kernel(
    unsigned* __restrict__ hist, unsigned* __restrict__ aux)
{
    __shared__ unsigned s[SCAN_CHUNK];
    int t = threadIdx.x;
    int i = blockIdx.x * SCAN_CHUNK + t;
    unsigned v = hist[i];
    s[t] = v;
    __syncthreads();
    #pragma unroll
    for (int o = 1; o < SCAN_CHUNK; o <<= 1) {
        unsigned x = (t >= o) ? s[t - o] : 0u;
        __syncthreads();
        s[t] += x;
        __syncthreads();
    }
    hist[i] = s[t] - v;
    if (t == SCAN_CHUNK - 1) aux[blockIdx.x] = s[t];
}

// ---- Sort step 2b: exclusive scan of chunk totals.
__global__ __launch_bounds__(NCHUNKS) void scan_aux_kernel(unsigned* __restrict__ aux)
{
    __shared__ unsigned s[NCHUNKS];
    int t = threadIdx.x;
    unsigned v = aux[t];
    s[t] = v;
    __syncthreads();
    #pragma unroll
    for (int o = 1; o < NCHUNKS; o <<= 1) {
        unsigned x = (t >= o) ? s[t - o] : 0u;
        __syncthreads();
        s[t] += x;
        __syncthreads();
    }
    aux[t] = s[t] - v;
}

// ---- Sort step 2c: add chunk offsets.
__global__ __launch_bounds__(SCAN_CHUNK) void scan_add_kernel(
    unsigned* __restrict__ hist, const unsigned* __restrict__ aux)
{
    int i = blockIdx.x * SCAN_CHUNK + threadIdx.x;
    hist[i] += aux[blockIdx.x];
}

// ---- Sort step 3: scatter ONE packed 16B slot {x,y,idx} per point
// (R11 wrote sxy + oidx = TWO random lines per point; this is one).
__global__ __launch_bounds__(256) void scatter_kernel(
    const f32x2* __restrict__ xy, unsigned* __restrict__ off,
    f32x4* __restrict__ slots)
{
    int p = blockIdx.x * 256 + threadIdx.x;
    f32x2 pt = __builtin_nontemporal_load(&xy[p]);
    unsigned pos = atomicAdd(&off[morton_key(pt)], 1u);
    f32x4 s = { pt.x, pt.y, __uint_as_float((unsigned)p), 0.0f };
    slots[pos] = s;
}

// ---- Main: Morton-ordered, full waves. Levels 0-3 from LDS (zero TA
// traffic, -25% lane-requests), 4-15 global. Grid-stride (1024 pts/block)
// amortizes the 28 KB LDS staging.
__global__ __launch_bounds__(256) void main_kernel(
    const f32x4* __restrict__ slots,
    const f32x2* __restrict__ grids,
    const f32x2* __restrict__ tables,
    f32x4* __restrict__ out,
    Params P)
{
    __shared__ f32x4 gstage[GPAD16];

    int tid = threadIdx.x;
    const f32x4* g4 = (const f32x4*)grids;
    #pragma unroll
    for (int i = 0; i < GPAD16 / 256; ++i)      // 7 coalesced iterations
        gstage[i * 256 + tid] = g4[i * 256 + tid];
    __syncthreads();
    const f32x2* gl = (const f32x2*)gstage;

    #pragma unroll 1
    for (int it = 0; it < 4; ++it) {
        int sp = blockIdx.x * 1024 + it * 256 + tid;
        f32x4 s = __builtin_nontemporal_load(&slots[sp]);
        f32x2 pt = { s.x, s.y };
        unsigned op = __float_as_uint(s.z);
        f32x4* o = out + (size_t)op * 8;

        f32x2 r[8];
        // ---- line 0: levels 0-7 (0-3 LDS, 4-7 global)
        #pragma unroll
        for (int j = 0; j < NLDS; ++j)
            r[j] = level_feat_lds(gl, P.goff[j], P.gstr[j], P.n[j], P.fn[j], pt);
        #pragma unroll
        for (int j = NLDS; j < 8; ++j)
            r[j] = level_feat(tables, j, P.n[j], P.fn[j], pt);
        #pragma unroll
        for (int q = 0; q < 4; ++q) {
            f32x4 v = { r[2 * q].x, r[2 * q].y, r[2 * q + 1].x, r[2 * q + 1].y };
            o[q] = v;
        }
        // ---- line 1: levels 8-15 (global)
        #pragma unroll
        for (int j = 0; j < 8; ++j)
            r[j] = level_feat(tables, 8 + j, P.n[8 + j], P.fn[8 + j], pt);
        #pragma unroll
        for (int q = 0; q < 4; ++q) {
            f32x4 v = { r[2 * q].x, r[2 * q].y, r[2 * q + 1].x, r[2 * q + 1].y };
            o[4 + q] = v;
        }
    }
}

// ---- Fallback (ws too small): single-pass kernel (~433 us).
__global__ __launch_bounds__(256, 6) void hashgrid2d_fallback(
    const f32x2* __restrict__ xy,
    const f32x2* __restrict__ tables,
    f32x4* __restrict__ out,
    Params P)
{
    __shared__ f32x4 lds[256 * 5];

    int tid = threadIdx.x;
    int p   = blockIdx.x * 256 + tid;

    f32x2 pt = __builtin_nontemporal_load(&xy[p]);
    size_t base = (size_t)blockIdx.x * 2048;

    #pragma unroll
    for (int b = 0; b < 2; ++b) {
        #pragma unroll
        for (int q = 0; q < 4; ++q) {
            float f[4];
            #pragma unroll
            for (int j = 0; j < 2; ++j) {
                int l = b * 8 + q * 2 + j;
                f32x2 r = level_feat(tables, l, P.n[l], P.fn[l], pt);
                f[j * 2 + 0] = r.x;
                f[j * 2 + 1] = r.y;
            }
            f32x4 v = { f[0], f[1], f[2], f[3] };
            lds[tid * 5 + q] = v;
        }
        __syncthreads();
        #pragma unroll
        for (int i = 0; i < 4; ++i) {
            int e  = i * 256 + tid;
            int pp = e >> 2;
            int q  = e & 3;
            f32x4 v = lds[pp * 5 + q];
            __builtin_nontemporal_store(v, &out[base + pp * 8 + b * 4 + q]);
        }
        __syncthreads();
    }
}

extern "C" void kernel_launch(void* const* d_in, const int* in_sizes, int n_in,
                              void* d_out, int out_size, void* d_ws, size_t ws_size,
                              hipStream_t stream) {
    const f32x2* xy     = (const f32x2*)d_in[0];
    const f32x2* tables = (const f32x2*)d_in[1];
    f32x4* out = (f32x4*)d_out;

    Params P;
    double b = pow(2048.0 / 16.0, 1.0 / 15.0);
    for (int l = 0; l < LVL; ++l) {
        int N = (int)llround(16.0 * pow(b, (double)l));
        P.n[l]  = N;
        P.fn[l] = (float)N;
    }
    int acc = 0;
    for (int li = 0; li < NLDS; ++li) {
        P.gstr[li] = P.n[li] | 1;            // odd stride -> bank spread
        P.goff[li] = acc;
        acc += P.gstr[li] * P.n[li];
    }

    // ws: hist 1MiB @0 | aux 1KiB @1MiB | slots 32MiB @2MiB | grids 32KiB @34MiB
    const size_t WS_NEED = (34u << 20) + (64u << 10);

    if (ws_size >= WS_NEED && acc <= GPAD16 * 2) {
        char* w = (char*)d_ws;
        unsigned* hist  = (unsigned*)(w);
        unsigned* aux   = (unsigned*)(w + (1u << 20));
        f32x4*    slots = (f32x4*)   (w + (2u << 20));
        f32x2*    grids = (f32x2*)   (w + (34u << 20));

        hipMemsetAsync(hist, 0, NBINS * sizeof(unsigned), stream);
        build_grids_kernel<<<(GPAD16 * 2 + 255) / 256, 256, 0, stream>>>(tables, grids, P);
        hist_kernel      <<<NPOINTS / 256, 256,        0, stream>>>(xy, hist);
        scan_local_kernel<<<NCHUNKS,       SCAN_CHUNK, 0, stream>>>(hist, aux);
        scan_aux_kernel  <<<1,             NCHUNKS,    0, stream>>>(aux);
        scan_add_kernel  <<<NCHUNKS,       SCAN_CHUNK, 0, stream>>>(hist, aux);
        scatter_kernel   <<<NPOINTS / 256, 256,        0, stream>>>(xy, hist, slots);
        main_kernel      <<<NPOINTS / 1024, 256,       0, stream>>>(slots, grids, tables, out, P);
    } else {
        hashgrid2d_fallback<<<NPOINTS / 256, 256, 0, stream>>>(xy, tables, out, P);
    }
}

// Round 15
// 432.579 us; speedup vs baseline: 1.0544x; 1.0544x over previous
//
#include <hip/hip_runtime.h>
#include <math.h>

#define NPOINTS (1 << 21)
#define LVL 16
#define TSIZE (1 << 19)
#define TMASK (TSIZE - 1)
#define PRIME2 2654435761u

// Morton bucket grid: 512 x 512 bins (~8 pts/bin) -- R11's proven config.
#define GBITS 9
#define GRES (1 << GBITS)
#define NBINS (1 << (2 * GBITS))
#define SCAN_CHUNK 1024
#define NCHUNKS (NBINS / SCAN_CHUNK)   // 256

// LDS dense grids for levels 0..2 (N=16,22,31; odd strides; 14,408 B)
#define G_TOT 1801                     // f32x2 entries (272 + 506 + 1023)

typedef float f32x2 __attribute__((ext_vector_type(2)));
typedef float f32x4 __attribute__((ext_vector_type(4)));

struct Params {
    int   n[LVL];
    float fn[LVL];
};

__device__ __forceinline__ unsigned part1by1(unsigned v) {
    v &= 0xFFFFu;
    v = (v | (v << 8)) & 0x00FF00FFu;
    v = (v | (v << 4)) & 0x0F0F0F0Fu;
    v = (v | (v << 2)) & 0x33333333u;
    v = (v | (v << 1)) & 0x55555555u;
    return v;
}

__device__ __forceinline__ unsigned morton_key(f32x2 pt) {
    int kx = (int)(pt.x * (float)GRES);
    int ky = (int)(pt.y * (float)GRES);
    kx = min(max(kx, 0), GRES - 1);
    ky = min(max(ky, 0), GRES - 1);
    return (part1by1((unsigned)ky) << 1) | part1by1((unsigned)kx);
}

// Plain 4-gather bilinear lookup (bit-identical to reference math).
__device__ __forceinline__ f32x2 level_feat(const f32x2* __restrict__ tables,
                                            int l, int N, float fN, f32x2 pt)
{
    float sx = pt.x * fN;
    float sy = pt.y * fN;
    float fx = floorf(sx);
    float fy = floorf(sy);
    float wx = sx - fx;
    float wy = sy - fy;
    int ix = (int)fx;
    int iy = (int)fy;

    int cx0 = (ix     >= N) ? ix - N     : ix;
    int cx1 = (ix + 1 >= N) ? ix + 1 - N : ix + 1;
    int cy0 = (iy     >= N) ? iy - N     : iy;
    int cy1 = (iy + 1 >= N) ? iy + 1 - N : iy + 1;

    unsigned hy0 = (unsigned)cy0 * PRIME2;
    unsigned hy1 = (unsigned)cy1 * PRIME2;

    const f32x2* tbl = tables + (size_t)l * TSIZE;
    f32x2 c00 = tbl[(int)(((unsigned)cx0 ^ hy0) & TMASK)];
    f32x2 c10 = tbl[(int)(((unsigned)cx1 ^ hy0) & TMASK)];
    f32x2 c01 = tbl[(int)(((unsigned)cx0 ^ hy1) & TMASK)];
    f32x2 c11 = tbl[(int)(((unsigned)cx1 ^ hy1) & TMASK)];

    float omx = 1.0f - wx, omy = 1.0f - wy;
    float f0x = c00.x * omx + c10.x * wx;
    float f0y = c00.y * omx + c10.y * wx;
    float f1x = c01.x * omx + c11.x * wx;
    float f1y = c01.y * omx + c11.y * wx;

    f32x2 r;
    r.x = f0x * omy + f1x * wy;
    r.y = f0y * omy + f1y * wy;
    return r;
}

// Same math, corners from the LDS dense grid; all layout compile-time.
template<int N, int ST, int BASE>
__device__ __forceinline__ f32x2 level_feat_lds(const f32x2* gl, f32x2 pt)
{
    const float fN = (float)N;
    float sx = pt.x * fN;
    float sy = pt.y * fN;
    float fx = floorf(sx);
    float fy = floorf(sy);
    float wx = sx - fx;
    float wy = sy - fy;
    int ix = (int)fx;
    int iy = (int)fy;

    int cx0 = (ix     >= N) ? ix - N     : ix;
    int cx1 = (ix + 1 >= N) ? ix + 1 - N : ix + 1;
    int cy0 = (iy     >= N) ? iy - N     : iy;
    int cy1 = (iy + 1 >= N) ? iy + 1 - N : iy + 1;

    int r0 = BASE + cy0 * ST;
    int r1 = BASE + cy1 * ST;
    f32x2 c00 = gl[r0 + cx0];
    f32x2 c10 = gl[r0 + cx1];
    f32x2 c01 = gl[r1 + cx0];
    f32x2 c11 = gl[r1 + cx1];

    float omx = 1.0f - wx, omy = 1.0f - wy;
    float f0x = c00.x * omx + c10.x * wx;
    float f0y = c00.y * omx + c10.y * wx;
    float f1x = c01.x * omx + c11.x * wx;
    float f1y = c01.y * omx + c11.y * wx;

    f32x2 r;
    r.x = f0x * omy + f1x * wy;
    r.y = f0y * omy + f1y * wy;
    return r;
}

// ---- Grid builder: de-hash levels 0..2 into dense grids in ws.
__global__ __launch_bounds__(256) void build_grids_kernel(
    const f32x2* __restrict__ tables, f32x2* __restrict__ grids)
{
    int t = blockIdx.x * 256 + threadIdx.x;
    if (t >= G_TOT) return;
    int l, base, st, N;
    if (t < 272)      { l = 0; base = 0;   st = 17; N = 16; }
    else if (t < 778) { l = 1; base = 272; st = 23; N = 22; }
    else              { l = 2; base = 778; st = 33; N = 31; }
    int local = t - base;
    int cy = local / st;
    int cx = local - cy * st;
    f32x2 v = { 0.0f, 0.0f };
    if (cx < N) {
        unsigned h = ((unsigned)cx ^ ((unsigned)cy * PRIME2)) & TMASK;
        v = tables[(size_t)l * TSIZE + h];
    }
    grids[t] = v;
}

// ---- Sort step 1: histogram of Morton keys.
__global__ __launch_bounds__(256) void hist_kernel(
    const f32x2* __restrict__ xy, unsigned* __restrict__ hist)
{
    int p = blockIdx.x * 256 + threadIdx.x;
    f32x2 pt = __builtin_nontemporal_load(&xy[p]);
    atomicAdd(&hist[morton_key(pt)], 1u);
}

// ---- Sort step 2a: per-chunk exclusive scan, chunk totals.
__global__ __launch_bounds__(SCAN_CHUNK) void scan_local_kernel(
    unsigned* __restrict__ hist, unsigned* __restrict__ aux)
{
    __shared__ unsigned s[SCAN_CHUNK];
    int t = threadIdx.x;
    int i = blockIdx.x * SCAN_CHUNK + t;
    unsigned v = hist[i];
    s[t] = v;
    __syncthreads();
    #pragma unroll
    for (int o = 1; o < SCAN_CHUNK; o <<= 1) {
        unsigned x = (t >= o) ? s[t - o] : 0u;
        __syncthreads();
        s[t] += x;
        __syncthreads();
    }
    hist[i] = s[t] - v;
    if (t == SCAN_CHUNK - 1) aux[blockIdx.x] = s[t];
}

// ---- Sort step 2b: exclusive scan of chunk totals.
__global__ __launch_bounds__(NCHUNKS) void scan_aux_kernel(unsigned* __restrict__ aux)
{
    __shared__ unsigned s[NCHUNKS];
    int t = threadIdx.x;
    unsigned v = aux[t];
    s[t] = v;
    __syncthreads();
    #pragma unroll
    for (int o = 1; o < NCHUNKS; o <<= 1) {
        unsigned x = (t >= o) ? s[t - o] : 0u;
        __syncthreads();
        s[t] += x;
        __syncthreads();
    }
    aux[t] = s[t] - v;
}

// ---- Sort step 3: scatter ONE packed 16B slot; chunk offset folded in
// (pos = local atomic + aux[chunk]) -> no scan_add pass at all.
__global__ __launch_bounds__(256) void scatter_kernel(
    const f32x2* __restrict__ xy, unsigned* __restrict__ hist,
    const unsigned* __restrict__ aux, f32x4* __restrict__ slots)
{
    int p = blockIdx.x * 256 + threadIdx.x;
    f32x2 pt = __builtin_nontemporal_load(&xy[p]);
    unsigned key = morton_key(pt);
    unsigned pos = atomicAdd(&hist[key], 1u) + aux[key >> 10];
    f32x4 s = { pt.x, pt.y, __uint_as_float((unsigned)p), 0.0f };
    slots[pos] = s;
}

// ---- Main: R11 structure (8192 blocks, 1 pt/thread, full waves) +
// levels 0-2 from LDS dense grids (compile-time layout; -18.75% of the
// global lane-requests at the ~1 granule/cy TCP wall).
__global__ __launch_bounds__(256) void main_kernel(
    const f32x4* __restrict__ slots,
    const f32x2* __restrict__ grids,
    const f32x2* __restrict__ tables,
    f32x4* __restrict__ out,
    Params P)
{
    __shared__ f32x2 gl[G_TOT + 7];

    int tid = threadIdx.x;
    #pragma unroll
    for (int i = 0; i < 8; ++i) {
        int t = i * 256 + tid;
        if (t < G_TOT) gl[t] = grids[t];
    }
    __syncthreads();

    int sp = blockIdx.x * 256 + tid;
    f32x4 s = __builtin_nontemporal_load(&slots[sp]);
    f32x2 pt = { s.x, s.y };
    unsigned op = __float_as_uint(s.z);
    f32x4* o = out + (size_t)op * 8;

    f32x2 r[8];
    // line 0: levels 0-2 LDS, 3-7 global
    r[0] = level_feat_lds<16, 17, 0  >(gl, pt);
    r[1] = level_feat_lds<22, 23, 272>(gl, pt);
    r[2] = level_feat_lds<31, 33, 778>(gl, pt);
    #pragma unroll
    for (int j = 3; j < 8; ++j)
        r[j] = level_feat(tables, j, P.n[j], P.fn[j], pt);
    #pragma unroll
    for (int q = 0; q < 4; ++q) {
        f32x4 v = { r[2 * q].x, r[2 * q].y, r[2 * q + 1].x, r[2 * q + 1].y };
        o[q] = v;
    }
    // line 1: levels 8-15 global
    #pragma unroll
    for (int j = 0; j < 8; ++j)
        r[j] = level_feat(tables, 8 + j, P.n[8 + j], P.fn[8 + j], pt);
    #pragma unroll
    for (int q = 0; q < 4; ++q) {
        f32x4 v = { r[2 * q].x, r[2 * q].y, r[2 * q + 1].x, r[2 * q + 1].y };
        o[4 + q] = v;
    }
}

// ---- Fallback (ws too small): single-pass kernel (~433 us).
__global__ __launch_bounds__(256, 6) void hashgrid2d_fallback(
    const f32x2* __restrict__ xy,
    const f32x2* __restrict__ tables,
    f32x4* __restrict__ out,
    Params P)
{
    __shared__ f32x4 lds[256 * 5];

    int tid = threadIdx.x;
    int p   = blockIdx.x * 256 + tid;

    f32x2 pt = __builtin_nontemporal_load(&xy[p]);
    size_t base = (size_t)blockIdx.x * 2048;

    #pragma unroll
    for (int b = 0; b < 2; ++b) {
        #pragma unroll
        for (int q = 0; q < 4; ++q) {
            float f[4];
            #pragma unroll
            for (int j = 0; j < 2; ++j) {
                int l = b * 8 + q * 2 + j;
                f32x2 r = level_feat(tables, l, P.n[l], P.fn[l], pt);
                f[j * 2 + 0] = r.x;
                f[j * 2 + 1] = r.y;
            }
            f32x4 v = { f[0], f[1], f[2], f[3] };
            lds[tid * 5 + q] = v;
        }
        __syncthreads();
        #pragma unroll
        for (int i = 0; i < 4; ++i) {
            int e  = i * 256 + tid;
            int pp = e >> 2;
            int q  = e & 3;
            f32x4 v = lds[pp * 5 + q];
            __builtin_nontemporal_store(v, &out[base + pp * 8 + b * 4 + q]);
        }
        __syncthreads();
    }
}

extern "C" void kernel_launch(void* const* d_in, const int* in_sizes, int n_in,
                              void* d_out, int out_size, void* d_ws, size_t ws_size,
                              hipStream_t stream) {
    const f32x2* xy     = (const f32x2*)d_in[0];
    const f32x2* tables = (const f32x2*)d_in[1];
    f32x4* out = (f32x4*)d_out;

    Params P;
    double b = pow(2048.0 / 16.0, 1.0 / 15.0);
    for (int l = 0; l < LVL; ++l) {
        int N = (int)llround(16.0 * pow(b, (double)l));
        P.n[l]  = N;
        P.fn[l] = (float)N;
    }

    // ws: hist 1MiB @0 | aux 1KiB @1MiB | grids 16KiB @(1MiB+64KiB) | slots 32MiB @2MiB
    const size_t WS_NEED = 34u << 20;

    if (ws_size >= WS_NEED) {
        char* w = (char*)d_ws;
        unsigned* hist  = (unsigned*)(w);
        unsigned* aux   = (unsigned*)(w + (1u << 20));
        f32x2*    grids = (f32x2*)   (w + (1u << 20) + (64u << 10));
        f32x4*    slots = (f32x4*)   (w + (2u << 20));

        hipMemsetAsync(hist, 0, NBINS * sizeof(unsigned), stream);
        build_grids_kernel<<<(G_TOT + 255) / 256, 256, 0, stream>>>(tables, grids);
        hist_kernel      <<<NPOINTS / 256, 256,        0, stream>>>(xy, hist);
        scan_local_kernel<<<NCHUNKS,       SCAN_CHUNK, 0, stream>>>(hist, aux);
        scan_aux_kernel  <<<1,             NCHUNKS,    0, stream>>>(aux);
        scatter_kernel   <<<NPOINTS / 256, 256,        0, stream>>>(xy, hist, aux, slots);
        main_kernel      <<<NPOINTS / 256, 256,        0, stream>>>(slots, grids, tables, out, P);
    } else {
        hashgrid2d_fallback<<<NPOINTS / 256, 256, 0, stream>>>(xy, tables, out, P);
    }
}

// Round 16
// 266.699 us; speedup vs baseline: 1.7103x; 1.6220x over previous
//
#include <hip/hip_runtime.h>
#include <math.h>

#define NPOINTS (1 << 21)
#define LVL 16
#define TSIZE (1 << 19)
#define TMASK (TSIZE - 1)
#define PRIME2 2654435761u

// Morton 512x512 (18-bit key). coarse = key>>8 (32x32), fine = key&255 (16x16).
#define GBITS 9
#define GRES (1 << GBITS)
#define SCAN_CHUNK 1024
#define CB 1024                        // coarse bins
#define PPB 8192                       // points per phase-1 block
#define NB1 (NPOINTS / PPB)            // 256 blocks
#define MSIZE (CB * NB1)               // 262144 matrix entries
#define NCHUNKS (MSIZE / SCAN_CHUNK)   // 256
#define CAP 2560                       // fine-sort LDS capacity (~2048 + 11 sd)

typedef float f32x2 __attribute__((ext_vector_type(2)));
typedef float f32x4 __attribute__((ext_vector_type(4)));

struct Params {
    int   n[LVL];
    float fn[LVL];
};

__device__ __forceinline__ unsigned part1by1(unsigned v) {
    v &= 0xFFFFu;
    v = (v | (v << 8)) & 0x00FF00FFu;
    v = (v | (v << 4)) & 0x0F0F0F0Fu;
    v = (v | (v << 2)) & 0x33333333u;
    v = (v | (v << 1)) & 0x55555555u;
    return v;
}

__device__ __forceinline__ unsigned morton_key(f32x2 pt) {
    int kx = (int)(pt.x * (float)GRES);
    int ky = (int)(pt.y * (float)GRES);
    kx = min(max(kx, 0), GRES - 1);
    ky = min(max(ky, 0), GRES - 1);
    return (part1by1((unsigned)ky) << 1) | part1by1((unsigned)kx);
}

// Plain 4-gather bilinear lookup (bit-identical to reference math).
__device__ __forceinline__ f32x2 level_feat(const f32x2* __restrict__ tables,
                                            int l, int N, float fN, f32x2 pt)
{
    float sx = pt.x * fN;
    float sy = pt.y * fN;
    float fx = floorf(sx);
    float fy = floorf(sy);
    float wx = sx - fx;
    float wy = sy - fy;
    int ix = (int)fx;
    int iy = (int)fy;

    int cx0 = (ix     >= N) ? ix - N     : ix;
    int cx1 = (ix + 1 >= N) ? ix + 1 - N : ix + 1;
    int cy0 = (iy     >= N) ? iy - N     : iy;
    int cy1 = (iy + 1 >= N) ? iy + 1 - N : iy + 1;

    unsigned hy0 = (unsigned)cy0 * PRIME2;
    unsigned hy1 = (unsigned)cy1 * PRIME2;

    const f32x2* tbl = tables + (size_t)l * TSIZE;
    f32x2 c00 = tbl[(int)(((unsigned)cx0 ^ hy0) & TMASK)];
    f32x2 c10 = tbl[(int)(((unsigned)cx1 ^ hy0) & TMASK)];
    f32x2 c01 = tbl[(int)(((unsigned)cx0 ^ hy1) & TMASK)];
    f32x2 c11 = tbl[(int)(((unsigned)cx1 ^ hy1) & TMASK)];

    float omx = 1.0f - wx, omy = 1.0f - wy;
    float f0x = c00.x * omx + c10.x * wx;
    float f0y = c00.y * omx + c10.y * wx;
    float f1x = c01.x * omx + c11.x * wx;
    float f1y = c01.y * omx + c11.y * wx;

    f32x2 r;
    r.x = f0x * omy + f1x * wy;
    r.y = f0y * omy + f1y * wy;
    return r;
}

// ---- Phase A1: per-block coarse histogram -> M[bin][block]. No atomics on
// global, no memset (every entry written).
__global__ __launch_bounds__(256) void hist1_kernel(
    const f32x2* __restrict__ xy, unsigned* __restrict__ M)
{
    __shared__ unsigned lh[CB];
    int tid = threadIdx.x, b = blockIdx.x;
    for (int k = tid; k < CB; k += 256) lh[k] = 0;
    __syncthreads();
    int base = b * PPB;
    #pragma unroll
    for (int i = 0; i < PPB / 256; ++i) {
        f32x2 pt = __builtin_nontemporal_load(&xy[base + i * 256 + tid]);
        atomicAdd(&lh[morton_key(pt) >> 8], 1u);
    }
    __syncthreads();
    for (int k = tid; k < CB; k += 256) M[k * NB1 + b] = lh[k];
}

// ---- Scan (proven kernels, exact same shapes): exclusive scan of M's
// 262144 entries in (bin, block) order = per-(block,bin) output bases.
__global__ __launch_bounds__(SCAN_CHUNK) void scan_local_kernel(
    unsigned* __restrict__ hist, unsigned* __restrict__ aux)
{
    __shared__ unsigned s[SCAN_CHUNK];
    int t = threadIdx.x;
    int i = blockIdx.x * SCAN_CHUNK + t;
    unsigned v = hist[i];
    s[t] = v;
    __syncthreads();
    #pragma unroll
    for (int o = 1; o < SCAN_CHUNK; o <<= 1) {
        unsigned x = (t >= o) ? s[t - o] : 0u;
        __syncthreads();
        s[t] += x;
        __syncthreads();
    }
    hist[i] = s[t] - v;
    if (t == SCAN_CHUNK - 1) aux[blockIdx.x] = s[t];
}

__global__ __launch_bounds__(NCHUNKS) void scan_aux_kernel(unsigned* __restrict__ aux)
{
    __shared__ unsigned s[NCHUNKS];
    int t = threadIdx.x;
    unsigned v = aux[t];
    s[t] = v;
    __syncthreads();
    #pragma unroll
    for (int o = 1; o < NCHUNKS; o <<= 1) {
        unsigned x = (t >= o) ? s[t - o] : 0u;
        __syncthreads();
        s[t] += x;
        __syncthreads();
    }
    aux[t] = s[t] - v;
}

// ---- Phase A2: aggregated scatter. LDS cursors (no global atomics);
// per-(block,bin) destination runs (avg 8 slots = 128 B) -> L2 line-merge.
__global__ __launch_bounds__(256) void scatter1_kernel(
    const f32x2* __restrict__ xy, const unsigned* __restrict__ M,
    const unsigned* __restrict__ aux, f32x4* __restrict__ slotsA)
{
    __shared__ unsigned cur[CB];
    int tid = threadIdx.x, b = blockIdx.x;
    for (int k = tid; k < CB; k += 256) {
        unsigned idx = (unsigned)k * NB1 + b;
        cur[k] = M[idx] + aux[idx >> 10];
    }
    __syncthreads();
    int base = b * PPB;
    #pragma unroll
    for (int i = 0; i < PPB / 256; ++i) {
        int p = base + i * 256 + tid;
        f32x2 pt = __builtin_nontemporal_load(&xy[p]);
        unsigned k = morton_key(pt) >> 8;
        unsigned pos = atomicAdd(&cur[k], 1u);
        f32x4 s = { pt.x, pt.y, __uint_as_float((unsigned)p), 0.0f };
        slotsA[pos] = s;
    }
}

// ---- Phase B: per-coarse-bin fine counting sort (LDS). Coarse-then-fine =
// full 18-bit Morton order (same as R11). Overflow tail copied verbatim
// (permutation always preserved; order is perf-only).
__global__ __launch_bounds__(256) void fine_kernel(
    const f32x4* __restrict__ slotsA, const unsigned* __restrict__ M,
    const unsigned* __restrict__ aux, f32x4* __restrict__ slotsB)
{
    __shared__ f32x4 buf[CAP];
    __shared__ unsigned fh[256];
    __shared__ unsigned fc[256];

    int tid = threadIdx.x;
    int k   = blockIdx.x;                       // coarse bin

    unsigned i0 = (unsigned)k * NB1;
    unsigned start = M[i0] + aux[i0 >> 10];
    unsigned end;
    if (k == CB - 1) end = NPOINTS;
    else {
        unsigned i1 = (unsigned)(k + 1) * NB1;
        end = M[i1] + aux[i1 >> 10];
    }
    unsigned n = end - start;
    unsigned m = n > CAP ? CAP : n;

    fh[tid] = 0;
    __syncthreads();
    for (unsigned i = tid; i < m; i += 256) {
        f32x4 s = slotsA[start + i];
        buf[i] = s;
        f32x2 pt = { s.x, s.y };
        atomicAdd(&fh[morton_key(pt) & 255u], 1u);
    }
    __syncthreads();
    unsigned v = fh[tid];
    fc[tid] = v;
    __syncthreads();
    #pragma unroll
    for (int o = 1; o < 256; o <<= 1) {
        unsigned x = (tid >= o) ? fc[tid - o] : 0u;
        __syncthreads();
        fc[tid] += x;
        __syncthreads();
    }
    unsigned excl = fc[tid] - v;
    __syncthreads();
    fc[tid] = excl;                             // reuse as cursor
    __syncthreads();
    for (unsigned i = tid; i < m; i += 256) {
        f32x4 s = buf[i];
        f32x2 pt = { s.x, s.y };
        unsigned r = atomicAdd(&fc[morton_key(pt) & 255u], 1u);
        slotsB[start + r] = s;
    }
    for (unsigned i = CAP + tid; i < n; i += 256)   // overflow: verbatim
        slotsB[start + i] = slotsA[start + i];
}

// ---- Main: R11 structure (proven 191 us), packed slots, all levels global.
__global__ __launch_bounds__(256) void main_kernel(
    const f32x4* __restrict__ slots,
    const f32x2* __restrict__ tables,
    f32x4* __restrict__ out,
    Params P)
{
    int sp = blockIdx.x * 256 + threadIdx.x;
    f32x4 s = __builtin_nontemporal_load(&slots[sp]);
    f32x2 pt = { s.x, s.y };
    unsigned op = __float_as_uint(s.z);
    f32x4* o = out + (size_t)op * 8;

    f32x2 r[8];
    #pragma unroll
    for (int j = 0; j < 8; ++j)
        r[j] = level_feat(tables, j, P.n[j], P.fn[j], pt);
    #pragma unroll
    for (int q = 0; q < 4; ++q) {
        f32x4 v = { r[2 * q].x, r[2 * q].y, r[2 * q + 1].x, r[2 * q + 1].y };
        o[q] = v;
    }
    #pragma unroll
    for (int j = 0; j < 8; ++j)
        r[j] = level_feat(tables, 8 + j, P.n[8 + j], P.fn[8 + j], pt);
    #pragma unroll
    for (int q = 0; q < 4; ++q) {
        f32x4 v = { r[2 * q].x, r[2 * q].y, r[2 * q + 1].x, r[2 * q + 1].y };
        o[4 + q] = v;
    }
}

// ---- Fallback (ws too small): single-pass kernel (~433 us).
__global__ __launch_bounds__(256, 6) void hashgrid2d_fallback(
    const f32x2* __restrict__ xy,
    const f32x2* __restrict__ tables,
    f32x4* __restrict__ out,
    Params P)
{
    __shared__ f32x4 lds[256 * 5];

    int tid = threadIdx.x;
    int p   = blockIdx.x * 256 + tid;

    f32x2 pt = __builtin_nontemporal_load(&xy[p]);
    size_t base = (size_t)blockIdx.x * 2048;

    #pragma unroll
    for (int b = 0; b < 2; ++b) {
        #pragma unroll
        for (int q = 0; q < 4; ++q) {
            float f[4];
            #pragma unroll
            for (int j = 0; j < 2; ++j) {
                int l = b * 8 + q * 2 + j;
                f32x2 r = level_feat(tables, l, P.n[l], P.fn[l], pt);
                f[j * 2 + 0] = r.x;
                f[j * 2 + 1] = r.y;
            }
            f32x4 v = { f[0], f[1], f[2], f[3] };
            lds[tid * 5 + q] = v;
        }
        __syncthreads();
        #pragma unroll
        for (int i = 0; i < 4; ++i) {
            int e  = i * 256 + tid;
            int pp = e >> 2;
            int q  = e & 3;
            f32x4 v = lds[pp * 5 + q];
            __builtin_nontemporal_store(v, &out[base + pp * 8 + b * 4 + q]);
        }
        __syncthreads();
    }
}

extern "C" void kernel_launch(void* const* d_in, const int* in_sizes, int n_in,
                              void* d_out, int out_size, void* d_ws, size_t ws_size,
                              hipStream_t stream) {
    const f32x2* xy     = (const f32x2*)d_in[0];
    const f32x2* tables = (const f32x2*)d_in[1];
    f32x4* out = (f32x4*)d_out;

    Params P;
    double b = pow(2048.0 / 16.0, 1.0 / 15.0);
    for (int l = 0; l < LVL; ++l) {
        int N = (int)llround(16.0 * pow(b, (double)l));
        P.n[l]  = N;
        P.fn[l] = (float)N;
    }

    // ws: M 1MiB @0 | aux 1KiB @1MiB | slotsA 32MiB @2MiB | slotsB 32MiB @34MiB
    const size_t WS_NEED = 66u << 20;

    if (ws_size >= WS_NEED) {
        char* w = (char*)d_ws;
        unsigned* M      = (unsigned*)(w);
        unsigned* aux    = (unsigned*)(w + (1u << 20));
        f32x4*    slotsA = (f32x4*)   (w + (2u << 20));
        f32x4*    slotsB = (f32x4*)   (w + (34u << 20));

        hist1_kernel     <<<NB1,           256,        0, stream>>>(xy, M);
        scan_local_kernel<<<NCHUNKS,       SCAN_CHUNK, 0, stream>>>(M, aux);
        scan_aux_kernel  <<<1,             NCHUNKS,    0, stream>>>(aux);
        scatter1_kernel  <<<NB1,           256,        0, stream>>>(xy, M, aux, slotsA);
        fine_kernel      <<<CB,            256,        0, stream>>>(slotsA, M, aux, slotsB);
        main_kernel      <<<NPOINTS / 256, 256,        0, stream>>>(slotsB, tables, out, P);
    } else {
        hashgrid2d_fallback<<<NPOINTS / 256, 256, 0, stream>>>(xy, tables, out, P);
    }
}

// Round 17
// 263.914 us; speedup vs baseline: 1.7283x; 1.0105x over previous
//
#include <hip/hip_runtime.h>
#include <math.h>

#define NPOINTS (1 << 21)
#define LVL 16
#define TSIZE (1 << 19)
#define TMASK (TSIZE - 1)
#define PRIME2 2654435761u

// Morton 512x512 (18-bit key). coarse = key>>8 (32x32), fine = key&255 (16x16).
#define GBITS 9
#define GRES (1 << GBITS)
#define SCAN_CHUNK 1024
#define CB 1024                        // coarse bins
#define PPB 8192                       // points per phase-1 block
#define NB1 (NPOINTS / PPB)            // 256 blocks
#define MSIZE (CB * NB1)               // 262144 matrix entries
#define NCHUNKS (MSIZE / SCAN_CHUNK)   // 256
#define CAP 2560                       // fine-sort LDS capacity (~2048 + 11 sd)

typedef float f32x2 __attribute__((ext_vector_type(2)));
typedef float f32x4 __attribute__((ext_vector_type(4)));

struct Params {
    int   n[LVL];
    float fn[LVL];
};

__device__ __forceinline__ unsigned part1by1(unsigned v) {
    v &= 0xFFFFu;
    v = (v | (v << 8)) & 0x00FF00FFu;
    v = (v | (v << 4)) & 0x0F0F0F0Fu;
    v = (v | (v << 2)) & 0x33333333u;
    v = (v | (v << 1)) & 0x55555555u;
    return v;
}

__device__ __forceinline__ unsigned morton_key(f32x2 pt) {
    int kx = (int)(pt.x * (float)GRES);
    int ky = (int)(pt.y * (float)GRES);
    kx = min(max(kx, 0), GRES - 1);
    ky = min(max(ky, 0), GRES - 1);
    return (part1by1((unsigned)ky) << 1) | part1by1((unsigned)kx);
}

// Plain 4-gather bilinear lookup (bit-identical to reference math).
__device__ __forceinline__ f32x2 level_feat(const f32x2* __restrict__ tables,
                                            int l, int N, float fN, f32x2 pt)
{
    float sx = pt.x * fN;
    float sy = pt.y * fN;
    float fx = floorf(sx);
    float fy = floorf(sy);
    float wx = sx - fx;
    float wy = sy - fy;
    int ix = (int)fx;
    int iy = (int)fy;

    int cx0 = (ix     >= N) ? ix - N     : ix;
    int cx1 = (ix + 1 >= N) ? ix + 1 - N : ix + 1;
    int cy0 = (iy     >= N) ? iy - N     : iy;
    int cy1 = (iy + 1 >= N) ? iy + 1 - N : iy + 1;

    unsigned hy0 = (unsigned)cy0 * PRIME2;
    unsigned hy1 = (unsigned)cy1 * PRIME2;

    const f32x2* tbl = tables + (size_t)l * TSIZE;
    f32x2 c00 = tbl[(int)(((unsigned)cx0 ^ hy0) & TMASK)];
    f32x2 c10 = tbl[(int)(((unsigned)cx1 ^ hy0) & TMASK)];
    f32x2 c01 = tbl[(int)(((unsigned)cx0 ^ hy1) & TMASK)];
    f32x2 c11 = tbl[(int)(((unsigned)cx1 ^ hy1) & TMASK)];

    float omx = 1.0f - wx, omy = 1.0f - wy;
    float f0x = c00.x * omx + c10.x * wx;
    float f0y = c00.y * omx + c10.y * wx;
    float f1x = c01.x * omx + c11.x * wx;
    float f1y = c01.y * omx + c11.y * wx;

    f32x2 r;
    r.x = f0x * omy + f1x * wy;
    r.y = f0y * omy + f1y * wy;
    return r;
}

// ---- Phase A1: per-block coarse histogram -> M[bin][block].
__global__ __launch_bounds__(256) void hist1_kernel(
    const f32x2* __restrict__ xy, unsigned* __restrict__ M)
{
    __shared__ unsigned lh[CB];
    int tid = threadIdx.x, b = blockIdx.x;
    for (int k = tid; k < CB; k += 256) lh[k] = 0;
    __syncthreads();
    int base = b * PPB;
    #pragma unroll
    for (int i = 0; i < PPB / 256; ++i) {
        f32x2 pt = __builtin_nontemporal_load(&xy[base + i * 256 + tid]);
        atomicAdd(&lh[morton_key(pt) >> 8], 1u);
    }
    __syncthreads();
    for (int k = tid; k < CB; k += 256) M[k * NB1 + b] = lh[k];
}

// ---- Scan: exclusive scan of M's 262144 entries (bin, block) order.
__global__ __launch_bounds__(SCAN_CHUNK) void scan_local_kernel(
    unsigned* __restrict__ hist, unsigned* __restrict__ aux)
{
    __shared__ unsigned s[SCAN_CHUNK];
    int t = threadIdx.x;
    int i = blockIdx.x * SCAN_CHUNK + t;
    unsigned v = hist[i];
    s[t] = v;
    __syncthreads();
    #pragma unroll
    for (int o = 1; o < SCAN_CHUNK; o <<= 1) {
        unsigned x = (t >= o) ? s[t - o] : 0u;
        __syncthreads();
        s[t] += x;
        __syncthreads();
    }
    hist[i] = s[t] - v;
    if (t == SCAN_CHUNK - 1) aux[blockIdx.x] = s[t];
}

__global__ __launch_bounds__(NCHUNKS) void scan_aux_kernel(unsigned* __restrict__ aux)
{
    __shared__ unsigned s[NCHUNKS];
    int t = threadIdx.x;
    unsigned v = aux[t];
    s[t] = v;
    __syncthreads();
    #pragma unroll
    for (int o = 1; o < NCHUNKS; o <<= 1) {
        unsigned x = (t >= o) ? s[t - o] : 0u;
        __syncthreads();
        s[t] += x;
        __syncthreads();
    }
    aux[t] = s[t] - v;
}

// ---- Phase A2: aggregated scatter via LDS cursors.
__global__ __launch_bounds__(256) void scatter1_kernel(
    const f32x2* __restrict__ xy, const unsigned* __restrict__ M,
    const unsigned* __restrict__ aux, f32x4* __restrict__ slotsA)
{
    __shared__ unsigned cur[CB];
    int tid = threadIdx.x, b = blockIdx.x;
    for (int k = tid; k < CB; k += 256) {
        unsigned idx = (unsigned)k * NB1 + b;
        cur[k] = M[idx] + aux[idx >> 10];
    }
    __syncthreads();
    int base = b * PPB;
    #pragma unroll
    for (int i = 0; i < PPB / 256; ++i) {
        int p = base + i * 256 + tid;
        f32x2 pt = __builtin_nontemporal_load(&xy[p]);
        unsigned k = morton_key(pt) >> 8;
        unsigned pos = atomicAdd(&cur[k], 1u);
        f32x4 s = { pt.x, pt.y, __uint_as_float((unsigned)p), 0.0f };
        slotsA[pos] = s;
    }
}

// ---- Phase B: per-coarse-bin fine counting sort (LDS).
__global__ __launch_bounds__(256) void fine_kernel(
    const f32x4* __restrict__ slotsA, const unsigned* __restrict__ M,
    const unsigned* __restrict__ aux, f32x4* __restrict__ slotsB)
{
    __shared__ f32x4 buf[CAP];
    __shared__ unsigned fh[256];
    __shared__ unsigned fc[256];

    int tid = threadIdx.x;
    int k   = blockIdx.x;

    unsigned i0 = (unsigned)k * NB1;
    unsigned start = M[i0] + aux[i0 >> 10];
    unsigned end;
    if (k == CB - 1) end = NPOINTS;
    else {
        unsigned i1 = (unsigned)(k + 1) * NB1;
        end = M[i1] + aux[i1 >> 10];
    }
    unsigned n = end - start;
    unsigned m = n > CAP ? CAP : n;

    fh[tid] = 0;
    __syncthreads();
    for (unsigned i = tid; i < m; i += 256) {
        f32x4 s = slotsA[start + i];
        buf[i] = s;
        f32x2 pt = { s.x, s.y };
        atomicAdd(&fh[morton_key(pt) & 255u], 1u);
    }
    __syncthreads();
    unsigned v = fh[tid];
    fc[tid] = v;
    __syncthreads();
    #pragma unroll
    for (int o = 1; o < 256; o <<= 1) {
        unsigned x = (tid >= o) ? fc[tid - o] : 0u;
        __syncthreads();
        fc[tid] += x;
        __syncthreads();
    }
    unsigned excl = fc[tid] - v;
    __syncthreads();
    fc[tid] = excl;
    __syncthreads();
    for (unsigned i = tid; i < m; i += 256) {
        f32x4 s = buf[i];
        f32x2 pt = { s.x, s.y };
        unsigned r = atomicAdd(&fc[morton_key(pt) & 255u], 1u);
        slotsB[start + r] = s;
    }
    for (unsigned i = CAP + tid; i < n; i += 256)
        slotsB[start + i] = slotsA[start + i];
}

// ---- Main: R16 structure + XCD-bijective block swizzle. Dispatch
// round-robins ord->XCD, so orig = (ord%8)*1024 + ord/8 gives each XCD a
// CONTIGUOUS Morton chunk of 1024 blocks; ~200 concurrent blocks slide
// along the chunk -> instantaneous hot table slice ~2-3 MB, fits XCD L2
// (R9's residency mechanism, spatial form).
__global__ __launch_bounds__(256) void main_kernel(
    const f32x4* __restrict__ slots,
    const f32x2* __restrict__ tables,
    f32x4* __restrict__ out,
    Params P)
{
    int bid = (blockIdx.x & 7) * 1024 + (blockIdx.x >> 3);   // 8192 blocks
    int sp  = bid * 256 + threadIdx.x;
    f32x4 s = __builtin_nontemporal_load(&slots[sp]);
    f32x2 pt = { s.x, s.y };
    unsigned op = __float_as_uint(s.z);
    f32x4* o = out + (size_t)op * 8;

    f32x2 r[8];
    #pragma unroll
    for (int j = 0; j < 8; ++j)
        r[j] = level_feat(tables, j, P.n[j], P.fn[j], pt);
    #pragma unroll
    for (int q = 0; q < 4; ++q) {
        f32x4 v = { r[2 * q].x, r[2 * q].y, r[2 * q + 1].x, r[2 * q + 1].y };
        o[q] = v;
    }
    #pragma unroll
    for (int j = 0; j < 8; ++j)
        r[j] = level_feat(tables, 8 + j, P.n[8 + j], P.fn[8 + j], pt);
    #pragma unroll
    for (int q = 0; q < 4; ++q) {
        f32x4 v = { r[2 * q].x, r[2 * q].y, r[2 * q + 1].x, r[2 * q + 1].y };
        o[4 + q] = v;
    }
}

// ---- Fallback (ws too small): single-pass kernel (~433 us).
__global__ __launch_bounds__(256, 6) void hashgrid2d_fallback(
    const f32x2* __restrict__ xy,
    const f32x2* __restrict__ tables,
    f32x4* __restrict__ out,
    Params P)
{
    __shared__ f32x4 lds[256 * 5];

    int tid = threadIdx.x;
    int p   = blockIdx.x * 256 + tid;

    f32x2 pt = __builtin_nontemporal_load(&xy[p]);
    size_t base = (size_t)blockIdx.x * 2048;

    #pragma unroll
    for (int b = 0; b < 2; ++b) {
        #pragma unroll
        for (int q = 0; q < 4; ++q) {
            float f[4];
            #pragma unroll
            for (int j = 0; j < 2; ++j) {
                int l = b * 8 + q * 2 + j;
                f32x2 r = level_feat(tables, l, P.n[l], P.fn[l], pt);
                f[j * 2 + 0] = r.x;
                f[j * 2 + 1] = r.y;
            }
            f32x4 v = { f[0], f[1], f[2], f[3] };
            lds[tid * 5 + q] = v;
        }
        __syncthreads();
        #pragma unroll
        for (int i = 0; i < 4; ++i) {
            int e  = i * 256 + tid;
            int pp = e >> 2;
            int q  = e & 3;
            f32x4 v = lds[pp * 5 + q];
            __builtin_nontemporal_store(v, &out[base + pp * 8 + b * 4 + q]);
        }
        __syncthreads();
    }
}

extern "C" void kernel_launch(void* const* d_in, const int* in_sizes, int n_in,
                              void* d_out, int out_size, void* d_ws, size_t ws_size,
                              hipStream_t stream) {
    const f32x2* xy     = (const f32x2*)d_in[0];
    const f32x2* tables = (const f32x2*)d_in[1];
    f32x4* out = (f32x4*)d_out;

    Params P;
    double b = pow(2048.0 / 16.0, 1.0 / 15.0);
    for (int l = 0; l < LVL; ++l) {
        int N = (int)llround(16.0 * pow(b, (double)l));
        P.n[l]  = N;
        P.fn[l] = (float)N;
    }

    // ws: M 1MiB @0 | aux 1KiB @1MiB | slotsA 32MiB @2MiB | slotsB 32MiB @34MiB
    const size_t WS_NEED = 66u << 20;

    if (ws_size >= WS_NEED) {
        char* w = (char*)d_ws;
        unsigned* M      = (unsigned*)(w);
        unsigned* aux    = (unsigned*)(w + (1u << 20));
        f32x4*    slotsA = (f32x4*)   (w + (2u << 20));
        f32x4*    slotsB = (f32x4*)   (w + (34u << 20));

        hist1_kernel     <<<NB1,           256,        0, stream>>>(xy, M);
        scan_local_kernel<<<NCHUNKS,       SCAN_CHUNK, 0, stream>>>(M, aux);
        scan_aux_kernel  <<<1,             NCHUNKS,    0, stream>>>(aux);
        scatter1_kernel  <<<NB1,           256,        0, stream>>>(xy, M, aux, slotsA);
        fine_kernel      <<<CB,            256,        0, stream>>>(slotsA, M, aux, slotsB);
        main_kernel      <<<NPOINTS / 256, 256,        0, stream>>>(slotsB, tables, out, P);
    } else {
        hashgrid2d_fallback<<<NPOINTS / 256, 256, 0, stream>>>(xy, tables, out, P);
    }
}